// Round 7
// baseline (234.340 us; speedup 1.0000x reference)
//
#include <hip/hip_runtime.h>
#include <hip/hip_bf16.h>

// ---------------------------------------------------------------------------
// CrossAttention on MI355X (gfx950) — v7: attention waves split over n
// (fixed-max softmax makes n-chunks independent): all-Q-in-registers,
// 64x64 O^T per wave, single end-of-kernel cross-wave reduction.
// LDS fragment reads per wave cut 3x vs v6. Other kernels = v6.
// ---------------------------------------------------------------------------

typedef unsigned short u16;
typedef __bf16 bf16x8 __attribute__((ext_vector_type(8)));
typedef float f32x4 __attribute__((ext_vector_type(4)));

__device__ inline f32x4 mfma16(bf16x8 a, bf16x8 b, f32x4 c) {
    return __builtin_amdgcn_mfma_f32_16x16x32_bf16(a, b, c, 0, 0, 0);
}

__device__ inline u16 f2bf(float f) {
    union { float f; unsigned u; } v; v.f = f;
    unsigned r = v.u + 0x7fffu + ((v.u >> 16) & 1u);
    return (u16)(r >> 16);
}

__device__ inline float bf2f(u16 x) {
    union { unsigned u; float f; } v; v.u = ((unsigned)x) << 16; return v.f;
}

__device__ inline unsigned pk_bf16(float a, float b) {
    union { float f; unsigned u; } x, y; x.f = a; y.f = b;
    return __builtin_amdgcn_perm(y.u + 0x8000u, x.u + 0x8000u, 0x07060302u);
}

__device__ inline void load_lds16(const void* g, void* l) {
    __builtin_amdgcn_global_load_lds(
        (const __attribute__((address_space(1))) void*)g,
        (__attribute__((address_space(3))) void*)l, 16, 0, 0);
}

// ---------------------------------------------------------------------------
__global__ __launch_bounds__(256) void cast_rows_kernel(const float* __restrict__ text,
                                                        const float* __restrict__ Wq,
                                                        const float* __restrict__ Wk,
                                                        const float* __restrict__ Wo,
                                                        const float* __restrict__ features,
                                                        u16* __restrict__ otext, u16* __restrict__ oWq,
                                                        u16* __restrict__ oWk, u16* __restrict__ oWo,
                                                        float* __restrict__ ssbuf) {
    int blk = blockIdx.x, tid = threadIdx.x;
    if (blk < 7168) {
        int i = blk * 256 + tid;
        const float* src; u16* dst; int off;
        if (i < 1048576)      { src = text; dst = otext; off = i; }
        else if (i < 1310720) { src = Wq;   dst = oWq;   off = i - 1048576; }
        else if (i < 1572864) { src = Wk;   dst = oWk;   off = i - 1310720; }
        else                  { src = Wo;   dst = oWo;   off = i - 1572864; }
        float4 v = ((const float4*)src)[off];
        uint2 p; p.x = pk_bf16(v.x, v.y); p.y = pk_bf16(v.z, v.w);
        ((uint2*)dst)[off] = p;
    } else {
        int row = (blk - 7168) * 4 + (tid >> 6);
        int lane = tid & 63;
        const float4* rp = (const float4*)(features + (size_t)row * 1024) + lane * 4;
        float ss = 0.0f;
        #pragma unroll
        for (int i = 0; i < 4; ++i) {
            float4 v = rp[i];
            ss += v.x * v.x + v.y * v.y + v.z * v.z + v.w * v.w;
        }
        #pragma unroll
        for (int m = 1; m < 64; m <<= 1) ss += __shfl_xor(ss, m, 64);
        if (lane == 0) ssbuf[row] = ss;
    }
}

// ---------------------------------------------------------------------------
__global__ __launch_bounds__(256) void normT_kernel(const float* __restrict__ features,
                                                    const float* __restrict__ ssbuf,
                                                    const float* __restrict__ g,
                                                    u16* __restrict__ feats_bf,
                                                    u16* __restrict__ Vt) {
    __shared__ __align__(16) u16 tile[64][72];
    int tid = threadIdx.x, b = blockIdx.z;
    int n0 = blockIdx.x * 64, d0 = blockIdx.y * 64;
    int r = tid >> 2, cs = (tid & 3) * 16;
    int grow = b * 1024 + n0 + r;

    float rs = rsqrtf(ssbuf[grow] * (1.0f / 1024.0f) + 1e-6f);
    const float4* src = (const float4*)(features + (size_t)grow * 1024 + d0 + cs);
    const float4* gp  = (const float4*)(g + d0 + cs);
    union { u16 s[16]; uint4 v[2]; } ob;
    #pragma unroll
    for (int i = 0; i < 4; ++i) {
        float4 v = src[i], gv = gp[i];
        ((unsigned*)ob.s)[i * 2]     = pk_bf16(v.x * rs * gv.x, v.y * rs * gv.y);
        ((unsigned*)ob.s)[i * 2 + 1] = pk_bf16(v.z * rs * gv.z, v.w * rs * gv.w);
    }
    uint4* dst = (uint4*)(feats_bf + (size_t)grow * 1024 + d0 + cs);
    dst[0] = ob.v[0]; dst[1] = ob.v[1];
    #pragma unroll
    for (int i = 0; i < 16; ++i) tile[r][cs + i] = ob.s[i];
    __syncthreads();
    union { u16 s[8]; uint4 v; } t0, t1;
    #pragma unroll
    for (int i = 0; i < 8; ++i) { t0.s[i] = tile[cs + i][r]; t1.s[i] = tile[cs + 8 + i][r]; }
    u16* tdst = Vt + ((size_t)(b * 1024 + d0 + r)) * 1024 + n0 + cs;
    *(uint4*)tdst = t0.v;
    *(uint4*)(tdst + 8) = t1.v;
}

// ---------------------------------------------------------------------------
__global__ __launch_bounds__(256) void rmsnorm_qk_kernel(u16* __restrict__ QK,
                                                         const float* __restrict__ g_q,
                                                         const float* __restrict__ g_k,
                                                         float qscale) {
    int tid = threadIdx.x;
    int row = blockIdx.x * 4 + (tid >> 6);
    int lane = tid & 63;
    const float* g = (row < 4096) ? g_q : g_k;
    float outsc = (row < 4096) ? qscale : 1.0f;

    u16* rp = QK + (size_t)row * 1024 + lane * 16;
    union { u16 s[16]; uint4 v[2]; } in;
    in.v[0] = *(const uint4*)rp;
    in.v[1] = *(const uint4*)(rp + 8);
    float x[16], ss = 0.0f;
    #pragma unroll
    for (int i = 0; i < 16; ++i) { x[i] = bf2f(in.s[i]); ss += x[i] * x[i]; }
    #pragma unroll
    for (int m = 1; m < 64; m <<= 1) ss += __shfl_xor(ss, m, 64);
    float rs = rsqrtf(ss * (1.0f / 1024.0f) + 1e-6f) * outsc;
    const float4* gp = (const float4*)(g + lane * 16);
    union { unsigned u[8]; uint4 v[2]; } ob;
    #pragma unroll
    for (int i = 0; i < 4; ++i) {
        float4 gv = gp[i];
        ob.u[i * 2]     = pk_bf16(x[i * 4 + 0] * rs * gv.x, x[i * 4 + 1] * rs * gv.y);
        ob.u[i * 2 + 1] = pk_bf16(x[i * 4 + 2] * rs * gv.z, x[i * 4 + 3] * rs * gv.w);
    }
    *(uint4*)rp = ob.v[0];
    *(uint4*)(rp + 8) = ob.v[1];
}

// ---------------------------------------------------------------------------
// 128x64-tile GEMM, BK=64 (v6 proven).
template <bool BF16OUT>
__device__ __forceinline__ void gemm64_bk64(const u16* __restrict__ A, const u16* __restrict__ B,
                                            const float* __restrict__ bias, void* __restrict__ Cout,
                                            int m_blk, int n_blk, int K, int N,
                                            u16* As, u16* Bs) {
    int tid = threadIdx.x, wave = tid >> 6, lane = tid & 63;
    int quad = lane >> 4, l15 = lane & 15;
    int wm = wave & 1, wn = wave >> 1;
    int arow = tid >> 2, ac = (tid & 3) * 8;

    f32x4 acc[4][2] = {};

    for (int k0 = 0; k0 < K; k0 += 64) {
        #pragma unroll
        for (int kh = 0; kh < 2; ++kh)
            #pragma unroll
            for (int rh = 0; rh < 2; ++rh)
                load_lds16(A + (size_t)(m_blk + rh * 64 + arow) * K + k0 + kh * 32 + ac,
                           As + kh * 4096 + rh * 2048 + (wave * 64) * 8);
        #pragma unroll
        for (int kh = 0; kh < 2; ++kh)
            load_lds16(B + (size_t)(n_blk + arow) * K + k0 + kh * 32 + ac,
                       Bs + kh * 2048 + (wave * 64) * 8);
        __syncthreads();
        #pragma unroll
        for (int kh = 0; kh < 2; ++kh) {
            bf16x8 af[4], bfr[2];
            #pragma unroll
            for (int t = 0; t < 4; ++t)
                af[t] = *(const bf16x8*)&As[kh * 4096 + (wm * 64 + t * 16 + l15) * 32 + quad * 8];
            #pragma unroll
            for (int t = 0; t < 2; ++t)
                bfr[t] = *(const bf16x8*)&Bs[kh * 2048 + (wn * 32 + t * 16 + l15) * 32 + quad * 8];
            #pragma unroll
            for (int mt = 0; mt < 4; ++mt)
                #pragma unroll
                for (int nt = 0; nt < 2; ++nt)
                    acc[mt][nt] = mfma16(af[mt], bfr[nt], acc[mt][nt]);
        }
        __syncthreads();
    }
    #pragma unroll
    for (int nt = 0; nt < 2; ++nt) {
        int col = n_blk + wn * 32 + nt * 16 + l15;
        float bv = bias[col];
        #pragma unroll
        for (int mt = 0; mt < 4; ++mt) {
            int row0 = m_blk + wm * 64 + mt * 16 + quad * 4;
            #pragma unroll
            for (int r = 0; r < 4; ++r) {
                float val = acc[mt][nt][r] + bv;
                if (BF16OUT) ((u16*)Cout)[(size_t)(row0 + r) * N + col] = f2bf(val);
                else       ((float*)Cout)[(size_t)(row0 + r) * N + col] = val;
            }
        }
    }
}

__global__ __launch_bounds__(256) void gemm_qk_kernel(const u16* __restrict__ text_bf,
                                                      const u16* __restrict__ Wq,
                                                      const u16* __restrict__ feats_bf,
                                                      const u16* __restrict__ Wk,
                                                      const float* __restrict__ b_q,
                                                      const float* __restrict__ b_k,
                                                      u16* __restrict__ QK) {
    __shared__ __align__(16) u16 As[2 * 128 * 32];
    __shared__ __align__(16) u16 Bs[2 * 64 * 32];
    int id = blockIdx.x;
    if (id < 512) {
        gemm64_bk64<true>(text_bf, Wq, b_q, QK, (id & 31) * 128, (id >> 5) * 64, 1024, 1024, As, Bs);
    } else {
        id -= 512;
        gemm64_bk64<true>(feats_bf, Wk, b_k, QK + 4096 * 1024,
                          (id & 63) * 128, (id >> 6) * 64, 1024, 1024, As, Bs);
    }
}

__global__ __launch_bounds__(256) void gemm_o_kernel(const u16* __restrict__ A,
                                                     const u16* __restrict__ B,
                                                     const float* __restrict__ bias,
                                                     float* __restrict__ C) {
    __shared__ __align__(16) u16 As[2 * 128 * 32];
    __shared__ __align__(16) u16 Bs[2 * 64 * 32];
    int id = blockIdx.x;
    gemm64_bk64<false>(A, B, bias, C, (id & 31) * 128, (id >> 5) * 64, 1024, 1024, As, Bs);
}

// ---------------------------------------------------------------------------
// Flash attention v7: waves split over n (strip=32 of each 128-chunk), all 64
// Q rows in registers as B-frags, O^T[64d][64m] + l accumulated per wave,
// one cross-wave tree reduction at the end. Fixed-max exp2 softmax (C-init
// -16; Q pre-scaled by 0.125*log2e).
__global__ __launch_bounds__(256, 2) void attn_kernel(const u16* __restrict__ Q,
                                                      const u16* __restrict__ K,
                                                      const u16* __restrict__ Vt,
                                                      u16* __restrict__ Out) {
    int bh = blockIdx.x, qt = blockIdx.y;
    int b = bh >> 4, h = bh & 15;
    int tid = threadIdx.x, wave = tid >> 6, lane = tid & 63;
    int quad = lane >> 4, l15 = lane & 15;

    __shared__ __align__(16) char smem[49152];
    u16* Ks = (u16*)smem;                                // [128 n][64 d], chunk^ (n&7)
    u16* Vs = (u16*)(smem + 16384);                      // [64 d][128 n], chunk^ (d&7)
    u16* Pw = (u16*)(smem + 32768) + wave * 2048;        // per-wave [64 m][32 n], chunk^(m&3)

    // Q B-frags for all 64 m rows: qf[mt][kh] = B[m=mt*16+l15][k=kh*32+quad*8+j]
    const u16* Qbase = Q + ((size_t)(b * 512 + qt * 64)) * 1024 + h * 64;
    bf16x8 qf[4][2];
    #pragma unroll
    for (int mt = 0; mt < 4; ++mt)
        #pragma unroll
        for (int kh = 0; kh < 2; ++kh)
            qf[mt][kh] = *(const bf16x8*)(Qbase + (size_t)(mt * 16 + l15) * 1024 + kh * 32 + quad * 8);

    int krl = lane >> 3, kcl = lane & 7;
    int vrl = lane >> 4, vcl = lane & 15;
    const u16* Kbase = K + ((size_t)(b * 1024)) * 1024 + h * 64;
    const u16* Vbase = Vt + ((size_t)(b * 1024 + h * 64)) * 1024;

    __bf16 onev = (__bf16)1.0f;
    bf16x8 ones = {onev, onev, onev, onev, onev, onev, onev, onev};

    f32x4 o[4][4] = {};   // o[dt][mt] = O^T[d=dt*16+quad*4+r][m=mt*16+l15] (partial, wave's n)
    f32x4 lac[4] = {};    // lac[mt]: l[m=mt*16+l15] (any reg/any quad)

    for (int n0 = 0; n0 < 1024; n0 += 128) {
        // ---- cooperative staging: K[128][64], V[64][128], XOR-swizzled chunks
        #pragma unroll
        for (int j = 0; j < 4; ++j) {
            int krow = wave * 32 + j * 8 + krl;
            load_lds16(Kbase + (size_t)(n0 + krow) * 1024 + (kcl ^ (krow & 7)) * 8,
                       Ks + (wave * 32 + j * 8) * 64);
            int vrow = wave * 16 + j * 4 + vrl;
            load_lds16(Vbase + (size_t)vrow * 1024 + n0 + (vcl ^ (vrow & 7)) * 8,
                       Vs + (wave * 16 + j * 4) * 128);
        }
        __syncthreads();

        int ns = wave * 32;  // this wave's n-strip within the chunk

        // ---- S^T for strip: 2 n-tiles x 4 m-tiles, then P into LDS
        #pragma unroll
        for (int nt = 0; nt < 2; ++nt) {
            int R = ns + nt * 16 + l15;
            bf16x8 kf0 = *(const bf16x8*)&Ks[R * 64 + ((quad) ^ (l15 & 7)) * 8];
            bf16x8 kf1 = *(const bf16x8*)&Ks[R * 64 + ((4 + quad) ^ (l15 & 7)) * 8];
            #pragma unroll
            for (int mt = 0; mt < 4; ++mt) {
                f32x4 z = {-16.0f, -16.0f, -16.0f, -16.0f};
                f32x4 s = mfma16(kf0, qf[mt][0], z);
                s = mfma16(kf1, qf[mt][1], s);
                uint2 pk;
                pk.x = pk_bf16(exp2f(s[0]), exp2f(s[1]));
                pk.y = pk_bf16(exp2f(s[2]), exp2f(s[3]));
                int cp = (nt * 2 + (quad >> 1)) ^ (l15 & 3);
                *(uint2*)&Pw[(mt * 16 + l15) * 32 + cp * 8 + (quad & 1) * 4] = pk;
            }
        }

        // ---- PV over strip (K=32): O^T += V^T.P^T ; l += ones.P^T
        bf16x8 pf[4];
        #pragma unroll
        for (int mt = 0; mt < 4; ++mt)
            pf[mt] = *(const bf16x8*)&Pw[(mt * 16 + l15) * 32 + (quad ^ (l15 & 3)) * 8];
        #pragma unroll
        for (int dt = 0; dt < 4; ++dt) {
            int d = dt * 16 + l15;
            bf16x8 vf = *(const bf16x8*)&Vs[d * 128 + ((wave * 4 + quad) ^ (l15 & 7)) * 8];
            #pragma unroll
            for (int mt = 0; mt < 4; ++mt)
                o[dt][mt] = mfma16(vf, pf[mt], o[dt][mt]);
        }
        #pragma unroll
        for (int mt = 0; mt < 4; ++mt)
            lac[mt] = mfma16(ones, pf[mt], lac[mt]);
        __syncthreads();
    }

    // ---- cross-wave reduction (tree): overlay smem with fp32 buffers
    float* rbuf0 = (float*)smem;                 // [64 m][68] (17408 B)
    float* rbuf1 = (float*)(smem + 17408);       // [64 m][68]
    float* lbuf0 = (float*)(smem + 34816);       // [64]
    float* lbuf1 = (float*)(smem + 35072);       // [64]

    if (wave >= 2) {
        float* rb = (wave == 2) ? rbuf0 : rbuf1;
        float* lb = (wave == 2) ? lbuf0 : lbuf1;
        #pragma unroll
        for (int dt = 0; dt < 4; ++dt)
            #pragma unroll
            for (int mt = 0; mt < 4; ++mt)
                *(f32x4*)&rb[(mt * 16 + l15) * 68 + dt * 16 + quad * 4] = o[dt][mt];
        if (quad == 0)
            #pragma unroll
            for (int mt = 0; mt < 4; ++mt) lb[mt * 16 + l15] = lac[mt][0];
    }
    __syncthreads();
    if (wave < 2) {
        float* rb = (wave == 0) ? rbuf0 : rbuf1;
        float* lb = (wave == 0) ? lbuf0 : lbuf1;
        #pragma unroll
        for (int dt = 0; dt < 4; ++dt)
            #pragma unroll
            for (int mt = 0; mt < 4; ++mt)
                o[dt][mt] += *(const f32x4*)&rb[(mt * 16 + l15) * 68 + dt * 16 + quad * 4];
        #pragma unroll
        for (int mt = 0; mt < 4; ++mt) lac[mt][0] += lb[mt * 16 + l15];
    }
    __syncthreads();
    if (wave == 1) {
        #pragma unroll
        for (int dt = 0; dt < 4; ++dt)
            #pragma unroll
            for (int mt = 0; mt < 4; ++mt)
                *(f32x4*)&rbuf1[(mt * 16 + l15) * 68 + dt * 16 + quad * 4] = o[dt][mt];
        if (quad == 0)
            #pragma unroll
            for (int mt = 0; mt < 4; ++mt) lbuf1[mt * 16 + l15] = lac[mt][0];
    }
    __syncthreads();
    if (wave == 0) {
        #pragma unroll
        for (int dt = 0; dt < 4; ++dt)
            #pragma unroll
            for (int mt = 0; mt < 4; ++mt)
                o[dt][mt] += *(const f32x4*)&rbuf1[(mt * 16 + l15) * 68 + dt * 16 + quad * 4];
        #pragma unroll
        for (int mt = 0; mt < 4; ++mt) {
            float il = 1.0f / (lac[mt][0] + lbuf1[mt * 16 + l15]);
            size_t obase = ((size_t)(b * 512 + qt * 64 + mt * 16 + l15)) * 1024 + h * 64 + quad * 4;
            #pragma unroll
            for (int dt = 0; dt < 4; ++dt) {
                uint2 pk;
                pk.x = pk_bf16(o[dt][mt][0] * il, o[dt][mt][1] * il);
                pk.y = pk_bf16(o[dt][mt][2] * il, o[dt][mt][3] * il);
                *(uint2*)(Out + obase + dt * 16) = pk;
            }
        }
    }
}

// ---------------------------------------------------------------------------
extern "C" void kernel_launch(void* const* d_in, const int* in_sizes, int n_in,
                              void* d_out, int out_size, void* d_ws, size_t ws_size,
                              hipStream_t stream) {
    const float* text     = (const float*)d_in[0];
    const float* features = (const float*)d_in[1];
    const float* W_q      = (const float*)d_in[2];
    const float* b_q      = (const float*)d_in[3];
    const float* W_k      = (const float*)d_in[4];
    const float* b_k      = (const float*)d_in[5];
    const float* W_o      = (const float*)d_in[6];
    const float* b_o      = (const float*)d_in[7];
    const float* g_feat   = (const float*)d_in[8];
    const float* g_q      = (const float*)d_in[9];
    const float* g_k      = (const float*)d_in[10];

    char* ws = (char*)d_ws;
    u16*   text_bf  = (u16*)(ws + 0);            //  8 MB [4096,1024]
    u16*   Wq_bf    = (u16*)(ws + 8388608);      //  2 MB
    u16*   Wk_bf    = (u16*)(ws + 10485760);     //  2 MB
    u16*   Wo_bf    = (u16*)(ws + 12582912);     //  2 MB
    u16*   feats_bf = (u16*)(ws + 14680064);     // 16 MB [8192,1024]
    u16*   Vt       = (u16*)(ws + 31457280);     // 16 MB [8][1024 d][1024 n]
    u16*   QKbuf    = (u16*)(ws + 48234496);     // 24 MB [12288,1024] (Q, then K)
    u16*   attn_bf  = (u16*)(ws + 73400320);     //  8 MB [4096,1024]
    float* ssbuf    = (float*)(ws + 81788928);   // 32 KB [8192]

    const float QSCALE = 0.18033688011112042f;   // 0.125 * log2(e)

    cast_rows_kernel<<<9216, 256, 0, stream>>>(text, W_q, W_k, W_o, features,
                                               text_bf, Wq_bf, Wk_bf, Wo_bf, ssbuf);
    normT_kernel<<<dim3(16, 16, 8), 256, 0, stream>>>(features, ssbuf, g_feat, feats_bf, Vt);
    gemm_qk_kernel<<<1536, 256, 0, stream>>>(text_bf, Wq_bf, feats_bf, Wk_bf, b_q, b_k, QKbuf);
    rmsnorm_qk_kernel<<<3072, 256, 0, stream>>>(QKbuf, g_q, g_k, QSCALE);
    attn_kernel<<<dim3(128, 8), 256, 0, stream>>>(QKbuf, QKbuf + 4096 * 1024, Vt, attn_bf);
    gemm_o_kernel<<<512, 256, 0, stream>>>(attn_bf, Wo_bf, b_o, (float*)d_out);
}

// Round 8
// 225.679 us; speedup vs baseline: 1.0384x; 1.0384x over previous
//
#include <hip/hip_runtime.h>
#include <hip/hip_bf16.h>

// ---------------------------------------------------------------------------
// CrossAttention on MI355X (gfx950) — v8: v6 base; attention rebuilt with
// double-buffered K/V staging (barrier -> prefetch next -> compute current:
// load latency hidden behind compute, one barrier/iter) and 32 Q rows/wave
// (K/V fragment reads per MFMA halved). m-split: no cross-wave reduction.
// ---------------------------------------------------------------------------

typedef unsigned short u16;
typedef __bf16 bf16x8 __attribute__((ext_vector_type(8)));
typedef float f32x4 __attribute__((ext_vector_type(4)));

__device__ inline f32x4 mfma16(bf16x8 a, bf16x8 b, f32x4 c) {
    return __builtin_amdgcn_mfma_f32_16x16x32_bf16(a, b, c, 0, 0, 0);
}

__device__ inline u16 f2bf(float f) {
    union { float f; unsigned u; } v; v.f = f;
    unsigned r = v.u + 0x7fffu + ((v.u >> 16) & 1u);
    return (u16)(r >> 16);
}

__device__ inline float bf2f(u16 x) {
    union { unsigned u; float f; } v; v.u = ((unsigned)x) << 16; return v.f;
}

__device__ inline unsigned pk_bf16(float a, float b) {
    union { float f; unsigned u; } x, y; x.f = a; y.f = b;
    return __builtin_amdgcn_perm(y.u + 0x8000u, x.u + 0x8000u, 0x07060302u);
}

__device__ inline void load_lds16(const void* g, void* l) {
    __builtin_amdgcn_global_load_lds(
        (const __attribute__((address_space(1))) void*)g,
        (__attribute__((address_space(3))) void*)l, 16, 0, 0);
}

// ---------------------------------------------------------------------------
__global__ __launch_bounds__(256) void cast_rows_kernel(const float* __restrict__ text,
                                                        const float* __restrict__ Wq,
                                                        const float* __restrict__ Wk,
                                                        const float* __restrict__ Wo,
                                                        const float* __restrict__ features,
                                                        u16* __restrict__ otext, u16* __restrict__ oWq,
                                                        u16* __restrict__ oWk, u16* __restrict__ oWo,
                                                        float* __restrict__ ssbuf) {
    int blk = blockIdx.x, tid = threadIdx.x;
    if (blk < 7168) {
        int i = blk * 256 + tid;
        const float* src; u16* dst; int off;
        if (i < 1048576)      { src = text; dst = otext; off = i; }
        else if (i < 1310720) { src = Wq;   dst = oWq;   off = i - 1048576; }
        else if (i < 1572864) { src = Wk;   dst = oWk;   off = i - 1310720; }
        else                  { src = Wo;   dst = oWo;   off = i - 1572864; }
        float4 v = ((const float4*)src)[off];
        uint2 p; p.x = pk_bf16(v.x, v.y); p.y = pk_bf16(v.z, v.w);
        ((uint2*)dst)[off] = p;
    } else {
        int row = (blk - 7168) * 4 + (tid >> 6);
        int lane = tid & 63;
        const float4* rp = (const float4*)(features + (size_t)row * 1024) + lane * 4;
        float ss = 0.0f;
        #pragma unroll
        for (int i = 0; i < 4; ++i) {
            float4 v = rp[i];
            ss += v.x * v.x + v.y * v.y + v.z * v.z + v.w * v.w;
        }
        #pragma unroll
        for (int m = 1; m < 64; m <<= 1) ss += __shfl_xor(ss, m, 64);
        if (lane == 0) ssbuf[row] = ss;
    }
}

// ---------------------------------------------------------------------------
__global__ __launch_bounds__(256) void normT_kernel(const float* __restrict__ features,
                                                    const float* __restrict__ ssbuf,
                                                    const float* __restrict__ g,
                                                    u16* __restrict__ feats_bf,
                                                    u16* __restrict__ Vt) {
    __shared__ __align__(16) u16 tile[64][72];
    int tid = threadIdx.x, b = blockIdx.z;
    int n0 = blockIdx.x * 64, d0 = blockIdx.y * 64;
    int r = tid >> 2, cs = (tid & 3) * 16;
    int grow = b * 1024 + n0 + r;

    float rs = rsqrtf(ssbuf[grow] * (1.0f / 1024.0f) + 1e-6f);
    const float4* src = (const float4*)(features + (size_t)grow * 1024 + d0 + cs);
    const float4* gp  = (const float4*)(g + d0 + cs);
    union { u16 s[16]; uint4 v[2]; } ob;
    #pragma unroll
    for (int i = 0; i < 4; ++i) {
        float4 v = src[i], gv = gp[i];
        ((unsigned*)ob.s)[i * 2]     = pk_bf16(v.x * rs * gv.x, v.y * rs * gv.y);
        ((unsigned*)ob.s)[i * 2 + 1] = pk_bf16(v.z * rs * gv.z, v.w * rs * gv.w);
    }
    uint4* dst = (uint4*)(feats_bf + (size_t)grow * 1024 + d0 + cs);
    dst[0] = ob.v[0]; dst[1] = ob.v[1];
    #pragma unroll
    for (int i = 0; i < 16; ++i) tile[r][cs + i] = ob.s[i];
    __syncthreads();
    union { u16 s[8]; uint4 v; } t0, t1;
    #pragma unroll
    for (int i = 0; i < 8; ++i) { t0.s[i] = tile[cs + i][r]; t1.s[i] = tile[cs + 8 + i][r]; }
    u16* tdst = Vt + ((size_t)(b * 1024 + d0 + r)) * 1024 + n0 + cs;
    *(uint4*)tdst = t0.v;
    *(uint4*)(tdst + 8) = t1.v;
}

// ---------------------------------------------------------------------------
__global__ __launch_bounds__(256) void rmsnorm_qk_kernel(u16* __restrict__ QK,
                                                         const float* __restrict__ g_q,
                                                         const float* __restrict__ g_k,
                                                         float qscale) {
    int tid = threadIdx.x;
    int row = blockIdx.x * 4 + (tid >> 6);
    int lane = tid & 63;
    const float* g = (row < 4096) ? g_q : g_k;
    float outsc = (row < 4096) ? qscale : 1.0f;

    u16* rp = QK + (size_t)row * 1024 + lane * 16;
    union { u16 s[16]; uint4 v[2]; } in;
    in.v[0] = *(const uint4*)rp;
    in.v[1] = *(const uint4*)(rp + 8);
    float x[16], ss = 0.0f;
    #pragma unroll
    for (int i = 0; i < 16; ++i) { x[i] = bf2f(in.s[i]); ss += x[i] * x[i]; }
    #pragma unroll
    for (int m = 1; m < 64; m <<= 1) ss += __shfl_xor(ss, m, 64);
    float rs = rsqrtf(ss * (1.0f / 1024.0f) + 1e-6f) * outsc;
    const float4* gp = (const float4*)(g + lane * 16);
    union { unsigned u[8]; uint4 v[2]; } ob;
    #pragma unroll
    for (int i = 0; i < 4; ++i) {
        float4 gv = gp[i];
        ob.u[i * 2]     = pk_bf16(x[i * 4 + 0] * rs * gv.x, x[i * 4 + 1] * rs * gv.y);
        ob.u[i * 2 + 1] = pk_bf16(x[i * 4 + 2] * rs * gv.z, x[i * 4 + 3] * rs * gv.w);
    }
    *(uint4*)rp = ob.v[0];
    *(uint4*)(rp + 8) = ob.v[1];
}

// ---------------------------------------------------------------------------
// 128x64-tile GEMM, BK=64 (v6 proven).
template <bool BF16OUT>
__device__ __forceinline__ void gemm64_bk64(const u16* __restrict__ A, const u16* __restrict__ B,
                                            const float* __restrict__ bias, void* __restrict__ Cout,
                                            int m_blk, int n_blk, int K, int N,
                                            u16* As, u16* Bs) {
    int tid = threadIdx.x, wave = tid >> 6, lane = tid & 63;
    int quad = lane >> 4, l15 = lane & 15;
    int wm = wave & 1, wn = wave >> 1;
    int arow = tid >> 2, ac = (tid & 3) * 8;

    f32x4 acc[4][2] = {};

    for (int k0 = 0; k0 < K; k0 += 64) {
        #pragma unroll
        for (int kh = 0; kh < 2; ++kh)
            #pragma unroll
            for (int rh = 0; rh < 2; ++rh)
                load_lds16(A + (size_t)(m_blk + rh * 64 + arow) * K + k0 + kh * 32 + ac,
                           As + kh * 4096 + rh * 2048 + (wave * 64) * 8);
        #pragma unroll
        for (int kh = 0; kh < 2; ++kh)
            load_lds16(B + (size_t)(n_blk + arow) * K + k0 + kh * 32 + ac,
                       Bs + kh * 2048 + (wave * 64) * 8);
        __syncthreads();
        #pragma unroll
        for (int kh = 0; kh < 2; ++kh) {
            bf16x8 af[4], bfr[2];
            #pragma unroll
            for (int t = 0; t < 4; ++t)
                af[t] = *(const bf16x8*)&As[kh * 4096 + (wm * 64 + t * 16 + l15) * 32 + quad * 8];
            #pragma unroll
            for (int t = 0; t < 2; ++t)
                bfr[t] = *(const bf16x8*)&Bs[kh * 2048 + (wn * 32 + t * 16 + l15) * 32 + quad * 8];
            #pragma unroll
            for (int mt = 0; mt < 4; ++mt)
                #pragma unroll
                for (int nt = 0; nt < 2; ++nt)
                    acc[mt][nt] = mfma16(af[mt], bfr[nt], acc[mt][nt]);
        }
        __syncthreads();
    }
    #pragma unroll
    for (int nt = 0; nt < 2; ++nt) {
        int col = n_blk + wn * 32 + nt * 16 + l15;
        float bv = bias[col];
        #pragma unroll
        for (int mt = 0; mt < 4; ++mt) {
            int row0 = m_blk + wm * 64 + mt * 16 + quad * 4;
            #pragma unroll
            for (int r = 0; r < 4; ++r) {
                float val = acc[mt][nt][r] + bv;
                if (BF16OUT) ((u16*)Cout)[(size_t)(row0 + r) * N + col] = f2bf(val);
                else       ((float*)Cout)[(size_t)(row0 + r) * N + col] = val;
            }
        }
    }
}

__global__ __launch_bounds__(256) void gemm_qk_kernel(const u16* __restrict__ text_bf,
                                                      const u16* __restrict__ Wq,
                                                      const u16* __restrict__ feats_bf,
                                                      const u16* __restrict__ Wk,
                                                      const float* __restrict__ b_q,
                                                      const float* __restrict__ b_k,
                                                      u16* __restrict__ QK) {
    __shared__ __align__(16) u16 As[2 * 128 * 32];
    __shared__ __align__(16) u16 Bs[2 * 64 * 32];
    int id = blockIdx.x;
    if (id < 512) {
        gemm64_bk64<true>(text_bf, Wq, b_q, QK, (id & 31) * 128, (id >> 5) * 64, 1024, 1024, As, Bs);
    } else {
        id -= 512;
        gemm64_bk64<true>(feats_bf, Wk, b_k, QK + 4096 * 1024,
                          (id & 63) * 128, (id >> 6) * 64, 1024, 1024, As, Bs);
    }
}

__global__ __launch_bounds__(256) void gemm_o_kernel(const u16* __restrict__ A,
                                                     const u16* __restrict__ B,
                                                     const float* __restrict__ bias,
                                                     float* __restrict__ C) {
    __shared__ __align__(16) u16 As[2 * 128 * 32];
    __shared__ __align__(16) u16 Bs[2 * 64 * 32];
    int id = blockIdx.x;
    gemm64_bk64<false>(A, B, bias, C, (id & 31) * 128, (id >> 5) * 64, 1024, 1024, As, Bs);
}

// ---------------------------------------------------------------------------
// Flash attention v8. Grid (bh=128, qt=4), block 256 = 4 waves, 32 Q rows/wave
// (m-split, no cross-wave reduction). Double-buffered K/V staging: per iter
// barrier -> prefetch chunk c+1 -> compute chunk c (prefetch in flight during
// compute; the barrier's vmcnt drain hits loads issued a full phase earlier).
// Fixed-max exp2 softmax (C-init -16; Q pre-scaled by 0.125*log2e).
// v6's proven swizzles and P layout throughout.
__global__ __launch_bounds__(256, 2) void attn_kernel(const u16* __restrict__ Q,
                                                      const u16* __restrict__ K,
                                                      const u16* __restrict__ Vt,
                                                      u16* __restrict__ Out) {
    int bh = blockIdx.x, qt = blockIdx.y;
    int b = bh >> 4, h = bh & 15;
    int tid = threadIdx.x, wave = tid >> 6, lane = tid & 63;
    int quad = lane >> 4, l15 = lane & 15;

    // LDS: Ks[2][64n][64d], Vs[2][64d][64n], P[4 waves][32 m][72]
    __shared__ __align__(16) u16 Ksb[2][64 * 64];
    __shared__ __align__(16) u16 Vsb[2][64 * 64];
    __shared__ __align__(16) u16 Plds[4][32 * 72];
    u16* Pw = &Plds[wave][0];

    // Q B-frags for this wave's 32 rows: qf[mt][kh], m = mt*16+l15, k = kh*32+quad*8+j
    const u16* Qbase = Q + ((size_t)(b * 512 + qt * 128 + wave * 32)) * 1024 + h * 64;
    bf16x8 qf[2][2];
    #pragma unroll
    for (int mt = 0; mt < 2; ++mt)
        #pragma unroll
        for (int kh = 0; kh < 2; ++kh)
            qf[mt][kh] = *(const bf16x8*)(Qbase + (size_t)(mt * 16 + l15) * 1024 + kh * 32 + quad * 8);

    int srl = lane >> 3, scl = lane & 7;
    const u16* Kbase = K + ((size_t)(b * 1024)) * 1024 + h * 64;
    const u16* Vbase = Vt + ((size_t)(b * 1024 + h * 64)) * 1024;

    __bf16 onev = (__bf16)1.0f;
    bf16x8 ones = {onev, onev, onev, onev, onev, onev, onev, onev};

    f32x4 o[4][2] = {};   // o[dt][mt] = O^T[d=dt*16+quad*4+r][m=mt*16+l15]
    f32x4 lac[2] = {};    // lac[mt][*] = l[m=mt*16+l15]

    // prologue: stage chunk 0 into buffer 0
    #pragma unroll
    for (int j = 0; j < 2; ++j) {
        int row = wave * 16 + j * 8 + srl;
        load_lds16(Kbase + (size_t)row * 1024 + (scl ^ srl) * 8, Ksb[0] + (wave * 16 + j * 8) * 64);
        load_lds16(Vbase + (size_t)row * 1024 + (scl ^ srl) * 8, Vsb[0] + (wave * 16 + j * 8) * 64);
    }

    for (int c = 0; c < 16; ++c) {
        __syncthreads();   // drains chunk c's loads (issued a full phase ago) + buffer reuse safety
        if (c < 15) {      // prefetch chunk c+1 into the other buffer (flies during compute)
            int n1 = (c + 1) * 64;
            #pragma unroll
            for (int j = 0; j < 2; ++j) {
                int row = wave * 16 + j * 8 + srl;
                load_lds16(Kbase + (size_t)(n1 + row) * 1024 + (scl ^ srl) * 8,
                           Ksb[(c + 1) & 1] + (wave * 16 + j * 8) * 64);
                load_lds16(Vbase + (size_t)row * 1024 + n1 + (scl ^ srl) * 8,
                           Vsb[(c + 1) & 1] + (wave * 16 + j * 8) * 64);
            }
        }
        const u16* Ks = Ksb[c & 1];
        const u16* Vs = Vsb[c & 1];

        // ---- S^T tiles (4 nt x 2 mt), C-init -16; P = 2^(s-16) -> LDS
        #pragma unroll
        for (int nt = 0; nt < 4; ++nt) {
            int R = nt * 16 + l15;
            int c1 = (quad ^ (l15 & 7)) * 8;
            bf16x8 kf0 = *(const bf16x8*)&Ks[R * 64 + c1];
            bf16x8 kf1 = *(const bf16x8*)&Ks[R * 64 + (c1 ^ 32)];
            #pragma unroll
            for (int mt = 0; mt < 2; ++mt) {
                f32x4 z = {-16.0f, -16.0f, -16.0f, -16.0f};
                f32x4 s = mfma16(kf0, qf[mt][0], z);
                s = mfma16(kf1, qf[mt][1], s);
                uint2 pk;
                pk.x = pk_bf16(exp2f(s[0]), exp2f(s[1]));
                pk.y = pk_bf16(exp2f(s[2]), exp2f(s[3]));
                *(uint2*)&Pw[(mt * 16 + l15) * 72 + nt * 16 + quad * 4] = pk;
            }
        }

        // ---- PV: O^T += V^T.P^T ; l += ones.P^T (P wave-private)
        bf16x8 pf[2][2];
        #pragma unroll
        for (int kc = 0; kc < 2; ++kc)
            #pragma unroll
            for (int mt = 0; mt < 2; ++mt)
                pf[kc][mt] = *(const bf16x8*)&Pw[(mt * 16 + l15) * 72 + kc * 32 + quad * 8];
        #pragma unroll
        for (int kc = 0; kc < 2; ++kc) {
            #pragma unroll
            for (int dt = 0; dt < 4; ++dt) {
                int d = dt * 16 + l15;
                bf16x8 vf = *(const bf16x8*)&Vs[d * 64 + ((kc * 4 + quad) ^ (l15 & 7)) * 8];
                #pragma unroll
                for (int mt = 0; mt < 2; ++mt)
                    o[dt][mt] = mfma16(vf, pf[kc][mt], o[dt][mt]);
            }
            #pragma unroll
            for (int mt = 0; mt < 2; ++mt)
                lac[mt] = mfma16(ones, pf[kc][mt], lac[mt]);
        }
    }

    // ---- epilogue (wave-private rows): O = O^T / l
    #pragma unroll
    for (int mt = 0; mt < 2; ++mt) {
        float il = 1.0f / lac[mt][0];
        size_t obase = ((size_t)(b * 512 + qt * 128 + wave * 32 + mt * 16 + l15)) * 1024
                       + h * 64 + quad * 4;
        #pragma unroll
        for (int dt = 0; dt < 4; ++dt) {
            uint2 pk;
            pk.x = pk_bf16(o[dt][mt][0] * il, o[dt][mt][1] * il);
            pk.y = pk_bf16(o[dt][mt][2] * il, o[dt][mt][3] * il);
            *(uint2*)(Out + obase + dt * 16) = pk;
        }
    }
}

// ---------------------------------------------------------------------------
extern "C" void kernel_launch(void* const* d_in, const int* in_sizes, int n_in,
                              void* d_out, int out_size, void* d_ws, size_t ws_size,
                              hipStream_t stream) {
    const float* text     = (const float*)d_in[0];
    const float* features = (const float*)d_in[1];
    const float* W_q      = (const float*)d_in[2];
    const float* b_q      = (const float*)d_in[3];
    const float* W_k      = (const float*)d_in[4];
    const float* b_k      = (const float*)d_in[5];
    const float* W_o      = (const float*)d_in[6];
    const float* b_o      = (const float*)d_in[7];
    const float* g_feat   = (const float*)d_in[8];
    const float* g_q      = (const float*)d_in[9];
    const float* g_k      = (const float*)d_in[10];

    char* ws = (char*)d_ws;
    u16*   text_bf  = (u16*)(ws + 0);            //  8 MB [4096,1024]
    u16*   Wq_bf    = (u16*)(ws + 8388608);      //  2 MB
    u16*   Wk_bf    = (u16*)(ws + 10485760);     //  2 MB
    u16*   Wo_bf    = (u16*)(ws + 12582912);     //  2 MB
    u16*   feats_bf = (u16*)(ws + 14680064);     // 16 MB [8192,1024]
    u16*   Vt       = (u16*)(ws + 31457280);     // 16 MB [8][1024 d][1024 n]
    u16*   QKbuf    = (u16*)(ws + 48234496);     // 24 MB [12288,1024] (Q, then K)
    u16*   attn_bf  = (u16*)(ws + 73400320);     //  8 MB [4096,1024]
    float* ssbuf    = (float*)(ws + 81788928);   // 32 KB [8192]

    const float QSCALE = 0.18033688011112042f;   // 0.125 * log2(e)

    cast_rows_kernel<<<9216, 256, 0, stream>>>(text, W_q, W_k, W_o, features,
                                               text_bf, Wq_bf, Wk_bf, Wo_bf, ssbuf);
    normT_kernel<<<dim3(16, 16, 8), 256, 0, stream>>>(features, ssbuf, g_feat, feats_bf, Vt);
    gemm_qk_kernel<<<1536, 256, 0, stream>>>(text_bf, Wq_bf, feats_bf, Wk_bf, b_q, b_k, QKbuf);
    rmsnorm_qk_kernel<<<3072, 256, 0, stream>>>(QKbuf, g_q, g_k, QSCALE);
    attn_kernel<<<dim3(128, 4), 256, 0, stream>>>(QKbuf, QKbuf + 4096 * 1024, Vt, attn_bf);
    gemm_o_kernel<<<512, 256, 0, stream>>>(attn_bf, Wo_bf, b_o, (float*)d_out);
}